// Round 8
// baseline (505.615 us; speedup 1.0000x reference)
//
#include <hip/hip_runtime.h>
#include <math.h>

#define TT 84
#define BB 96
#define GB 6            // batches per group
#define NG 16           // groups (NG*GB == BB)
#define NTOK (TT*BB)
#define RW4 6           // float4s per act row: 24 floats = [fwd 10 | pad 2 | bwd 10 | pad 2]

// Gate-argument pre-scaling folded into weights/biases:
//  r,z rows scaled by -log2(e)   -> sigm(a) = rcp(1 + exp2(arg))
//  n rows scaled by -2*log2(e)   -> tanh(x) = 2*rcp(1 + exp2(arg)) - 1
#define S_RZ (-1.4426950408889634f)
#define S_N  (-2.8853900817779268f)

typedef float v2f __attribute__((ext_vector_type(2)));
typedef float v4f __attribute__((ext_vector_type(4)));

__device__ __forceinline__ float frcp(float x)  { return __builtin_amdgcn_rcpf(x); }
__device__ __forceinline__ float fexp2(float x) { return __builtin_amdgcn_exp2f(x); }
__device__ __forceinline__ v2f   fma2(v2f a, v2f b, v2f c) {
    return __builtin_elementwise_fma(a, b, c);   // -> v_pk_fma_f32
}

// ---------------- layer-0 projection: emb gather + E=400 dot (pre-scaled) ----
// xp row layout (30 floats): [r0 z0 r1 z1 ... r9 z9 | n0..n9]
__global__ __launch_bounds__(256) void proj0_kernel(
    const int* __restrict__ x, const float* __restrict__ emb,
    const float* __restrict__ wih0, const float* __restrict__ bih0,
    float* __restrict__ xp, unsigned int* __restrict__ bar)
{
    if (blockIdx.x == 0 && threadIdx.x == 0) bar[0] = 0u;  // re-zero grid barrier
    __shared__ float4 xrow[32][100];   // 32 tokens x 400 floats
    const int tok0 = blockIdx.x * 32;
    for (int u = threadIdx.x; u < 32*100; u += 256) {
        int tk = u / 100, i4 = u % 100;
        int row = x[tok0 + tk];
        xrow[tk][i4] = ((const float4*)emb)[row*100 + i4];
    }
    __syncthreads();
    const int g64 = threadIdx.x & 63;
    const int q   = threadIdx.x >> 6;          // 0..3, 8 tokens each
    if (g64 >= 60) return;
    const int dir = g64 / 30, gg = g64 % 30;
    const float sc = (gg < 20) ? S_RZ : S_N;
    const float bias = bih0[dir*30 + gg];
    // interleaved output index
    const int ch  = (gg < 20) ? (gg % 10) : (gg - 20);
    const int idx = (gg < 20) ? (ch*2 + gg/10) : (20 + ch);
    float acc[8];
    #pragma unroll
    for (int c = 0; c < 8; ++c) acc[c] = bias;
    const float4* w4 = ((const float4*)wih0) + (dir*30 + gg)*100;
    for (int i4 = 0; i4 < 100; ++i4) {
        float4 w = w4[i4];
        #pragma unroll
        for (int c = 0; c < 8; ++c) {
            float4 xv = xrow[q*8 + c][i4];
            acc[c] += w.x*xv.x + w.y*xv.y + w.z*xv.z + w.w*xv.w;
        }
    }
    #pragma unroll
    for (int c = 0; c < 8; ++c) {
        int tok = tok0 + q*8 + c;
        int t = tok / BB, b = tok % BB;
        xp[((size_t)((dir*TT + t)*BB + b))*30 + idx] = acc[c]*sc;
    }
}

// proj over 20 channels from a padded 24-float act row
__device__ __forceinline__ void proj20(
    const float4* A, const float* wpr, const float* wpz, const float* wpn,
    float bir, float biz, float bin, float& xr, float& xz, float& xn)
{
    float a[24];
    #pragma unroll
    for (int q = 0; q < 6; ++q) {
        a[4*q]=A[q].x; a[4*q+1]=A[q].y; a[4*q+2]=A[q].z; a[4*q+3]=A[q].w;
    }
    xr = bir; xz = biz; xn = bin;
    #pragma unroll
    for (int c = 0; c < 20; ++c) {
        float av = a[c + (c >= 10 ? 2 : 0)];
        xr = fmaf(wpr[c], av, xr); xz = fmaf(wpz[c], av, xz); xn = fmaf(wpn[c], av, xn);
    }
}

// GRU gate math for one cell (pre-scaled pk weights)
__device__ __forceinline__ float gru_gates(
    v2f RZ, float XN,
    const v2f* w5r, const v2f* w5z, const v2f* w5n,
    v2f br2, v2f bz2, v2f bn2,
    v2f H0, v2f H1, v2f H2, v2f H3, v2f H4, float hown)
{
    v2f ar  = fma2(w5r[0], H0, br2);
    v2f az  = fma2(w5z[0], H0, bz2);
    v2f an2 = fma2(w5n[0], H0, bn2);
    ar = fma2(w5r[1], H1, ar); az = fma2(w5z[1], H1, az); an2 = fma2(w5n[1], H1, an2);
    ar = fma2(w5r[2], H2, ar); az = fma2(w5z[2], H2, az); an2 = fma2(w5n[2], H2, an2);
    ar = fma2(w5r[3], H3, ar); az = fma2(w5z[3], H3, az); an2 = fma2(w5n[3], H3, an2);
    ar = fma2(w5r[4], H4, ar); az = fma2(w5z[4], H4, az); an2 = fma2(w5n[4], H4, an2);
    float r  = frcp(1.f + fexp2((RZ.x + ar.x) + ar.y));
    float z  = frcp(1.f + fexp2((RZ.y + az.x) + az.y));
    float an = fmaf(r, an2.x + an2.y, XN);
    float n  = fmaf(2.f, frcp(1.f + fexp2(an)), -1.f);
    return n + z*(hown - n);
}

// ---------------- dual scan: fwd+bwd of one batch fused per lane -------------
// One 60-lane wave runs all 12 sequences: lane (bl,j) advances the fwd cell at
// t=s AND the bwd cell at t=83-s each step. Two independent chains per lane
// hide dependency stalls under each other's issue. act4 columns are disjoint
// (fwd 0-9, bwd 12-21); rows never collide (s != 83-s).
template<bool LAST>
__device__ __forceinline__ void scan_dual(
    const float* __restrict__ xpF, const float* __restrict__ xpB,
    const float* __restrict__ whF, const float* __restrict__ bhF,
    const float* __restrict__ whB, const float* __restrict__ bhB,
    float* __restrict__ arow, float* __restrict__ actG,
    int bl, int j, bool act_ln, int b)
{
    v2f wrF[5], wzF[5], wnF[5], wrB[5], wzB[5], wnB[5];
    {
        const v2f* f0 = (const v2f*)(whF + j*10);
        const v2f* f1 = (const v2f*)(whF + (10+j)*10);
        const v2f* f2 = (const v2f*)(whF + (20+j)*10);
        const v2f* b0 = (const v2f*)(whB + j*10);
        const v2f* b1 = (const v2f*)(whB + (10+j)*10);
        const v2f* b2 = (const v2f*)(whB + (20+j)*10);
        #pragma unroll
        for (int q = 0; q < 5; ++q) {
            wrF[q] = f0[q] * S_RZ;  wzF[q] = f1[q] * S_RZ;  wnF[q] = f2[q] * S_N;
            wrB[q] = b0[q] * S_RZ;  wzB[q] = b1[q] * S_RZ;  wnB[q] = b2[q] * S_N;
        }
    }
    const v2f brF = {bhF[j]*S_RZ, 0.f}, bzF = {bhF[10+j]*S_RZ, 0.f}, bnF = {bhF[20+j]*S_N, 0.f};
    const v2f brB = {bhB[j]*S_RZ, 0.f}, bzB = {bhB[10+j]*S_RZ, 0.f}, bnB = {bhB[20+j]*S_N, 0.f};

    v2f HF0={0,0}, HF1={0,0}, HF2={0,0}, HF3={0,0}, HF4={0,0};
    v2f HB0={0,0}, HB1={0,0}, HB2={0,0}, HB3={0,0}, HB4={0,0};
    float hoF = 0.f, hoB = 0.f;

    const int xoff = 2*j, noff = 20 + j;
    // 2-deep prefetch per dir (halves 0/1)
    v2f  rzF0 = *(const v2f*)(xpF + (size_t)(0*BB + b)*30 + xoff);
    float xnF0 = xpF[(size_t)(0*BB + b)*30 + noff];
    v2f  rzF1 = *(const v2f*)(xpF + (size_t)(1*BB + b)*30 + xoff);
    float xnF1 = xpF[(size_t)(1*BB + b)*30 + noff];
    v2f  rzB0 = *(const v2f*)(xpB + (size_t)((TT-1)*BB + b)*30 + xoff);
    float xnB0 = xpB[(size_t)((TT-1)*BB + b)*30 + noff];
    v2f  rzB1 = *(const v2f*)(xpB + (size_t)((TT-2)*BB + b)*30 + xoff);
    float xnB1 = xpB[(size_t)((TT-2)*BB + b)*30 + noff];

    int tF = 0, tB = TT-1;

    #define DUAL_STEP(RZF, XNF, RZB, XNB)                                     \
    {                                                                         \
        float hnF = gru_gates(RZF, XNF, wrF, wzF, wnF, brF, bzF, bnF,         \
                              HF0,HF1,HF2,HF3,HF4, hoF);                      \
        float hnB = gru_gates(RZB, XNB, wrB, wzB, wnB, brB, bzB, bnB,         \
                              HB0,HB1,HB2,HB3,HB4, hoB);                      \
        hoF = hnF; hoB = hnB;                                                 \
        int rowF = (tF*GB + bl)*24;                                           \
        int rowB = (tB*GB + bl)*24 + 12;                                      \
        arow[rowF + j] = hnF;                         /* ds_write */          \
        arow[rowB + j] = hnB;                         /* ds_write */          \
        const v4f* hrF = (const v4f*)(arow + rowF);                           \
        v4f haF = hrF[0], hbF = hrF[1];                                       \
        v2f hcF = *(const v2f*)(arow + rowF + 8);                             \
        const v4f* hrB = (const v4f*)(arow + rowB);                           \
        v4f haB = hrB[0], hbB = hrB[1];                                       \
        v2f hcB = *(const v2f*)(arow + rowB + 8);                             \
        HF0=haF.xy; HF1=haF.zw; HF2=hbF.xy; HF3=hbF.zw; HF4=hcF;              \
        HB0=haB.xy; HB1=haB.zw; HB2=hbB.xy; HB3=hbB.zw; HB4=hcB;              \
        __builtin_amdgcn_sched_barrier(0);                                    \
        if (LAST) { if (act_ln) {                                             \
            actG[(size_t)(tF*BB + b)*20 + j]      = hnF;                      \
            actG[(size_t)(tB*BB + b)*20 + 10 + j] = hnB; } }                  \
    }

    #pragma unroll 1
    for (int s = 0; s < TT; s += 2) {
        // half 0
        DUAL_STEP(rzF0, xnF0, rzB0, xnB0)
        {
            int tpF = tF + 2; tpF = tpF > TT-1 ? TT-1 : tpF;
            int tpB = tB - 2; tpB = tpB < 0 ? 0 : tpB;
            const float* pf = xpF + (size_t)(tpF*BB + b)*30;
            const float* pb = xpB + (size_t)(tpB*BB + b)*30;
            rzF0 = *(const v2f*)(pf + xoff); xnF0 = pf[noff];
            rzB0 = *(const v2f*)(pb + xoff); xnB0 = pb[noff];
            tF += 1; tB -= 1;
        }
        // half 1
        DUAL_STEP(rzF1, xnF1, rzB1, xnB1)
        {
            int tpF = tF + 2; tpF = tpF > TT-1 ? TT-1 : tpF;
            int tpB = tB - 2; tpB = tpB < 0 ? 0 : tpB;
            const float* pf = xpF + (size_t)(tpF*BB + b)*30;
            const float* pb = xpB + (size_t)(tpB*BB + b)*30;
            rzF1 = *(const v2f*)(pf + xoff); xnF1 = pf[noff];
            rzB1 = *(const v2f*)(pb + xoff); xnB1 = pb[noff];
            tF += 1; tB -= 1;
        }
    }
    #undef DUAL_STEP
}

// ---------------- mega: all 10 layers + head, 16 blocks x 256 ----------------
__global__ __launch_bounds__(256, 1) void mega_kernel(
    float* __restrict__ xp,             // read-write: layer-l inputs, overwritten per layer
    const float* __restrict__ whh0, const float* __restrict__ bhh0,
    const float* __restrict__ wih,  const float* __restrict__ bih,
    const float* __restrict__ whh,  const float* __restrict__ bhh,
    const float* __restrict__ lin_w, const float* __restrict__ lin_b,
    float* __restrict__ actG, unsigned int* __restrict__ bar,
    float* __restrict__ out)
{
    __shared__ float4 act4[TT*GB*RW4];    // 48384 B, single buffer

    const int tid  = threadIdx.x;
    const int grp  = blockIdx.x;
    const int lane = tid & 63;

    // scan mapping (wave 0 only): lane = (bl, j), handles fwd AND bwd of batch bl
    int bl = lane / 10; if (bl > 5) bl = 5;
    int j  = lane - bl*10; if (j > 9) j = 9;
    const bool act_ln = (lane < 60);
    const int b  = grp*GB + bl;

    // boundary-proj mapping (240 of 256 threads: 2 t-halves x 2 dir x 6 b x 10 ch)
    const int half = tid / 120;
    const int prr  = tid % 120;
    const int dp   = prr / 60;
    const int prr2 = prr % 60;
    const int blp  = prr2 / 10;
    const int jp   = prr2 % 10;

    float* xpF = xp;
    float* xpB = xp + (size_t)TT*BB*30;

    #pragma unroll 1
    for (int l = 0; l < 9; ++l) {
        if (tid < 64) {
            const float* whF = (l == 0) ? whh0            : (whh + (size_t)((l-1)*2    )*300);
            const float* whB = (l == 0) ? (whh0 + 300)    : (whh + (size_t)((l-1)*2 + 1)*300);
            const float* bhF = (l == 0) ? bhh0            : (bhh + (size_t)((l-1)*2    )*30);
            const float* bhB = (l == 0) ? (bhh0 + 30)     : (bhh + (size_t)((l-1)*2 + 1)*30);
            scan_dual<false>(xpF, xpB, whF, bhF, whB, bhB,
                             (float*)act4, actG, bl, j, act_ln, b);
        }
        __syncthreads();
        // boundary pass: xp for layer l+1 from act4, all 4 waves
        if (tid < 240) {
            const float* wi = wih + (size_t)(l*2 + dp)*600;
            const float* bi = bih + (size_t)(l*2 + dp)*30;
            float wpr[20], wpz[20], wpn[20];
            {
                const float4* p0 = (const float4*)(wi + jp*20);
                const float4* p1 = (const float4*)(wi + (10+jp)*20);
                const float4* p2 = (const float4*)(wi + (20+jp)*20);
                #pragma unroll
                for (int q = 0; q < 5; ++q) {
                    float4 a = p0[q]; wpr[4*q]=a.x*S_RZ; wpr[4*q+1]=a.y*S_RZ; wpr[4*q+2]=a.z*S_RZ; wpr[4*q+3]=a.w*S_RZ;
                    float4 c = p1[q]; wpz[4*q]=c.x*S_RZ; wpz[4*q+1]=c.y*S_RZ; wpz[4*q+2]=c.z*S_RZ; wpz[4*q+3]=c.w*S_RZ;
                    float4 d = p2[q]; wpn[4*q]=d.x*S_N;  wpn[4*q+1]=d.y*S_N;  wpn[4*q+2]=d.z*S_N;  wpn[4*q+3]=d.w*S_N;
                }
            }
            const float bir = bi[jp]*S_RZ, biz = bi[10+jp]*S_RZ, bin = bi[20+jp]*S_N;
            const int bg = grp*GB + blp;
            #pragma unroll 1
            for (int t = half*(TT/2); t < (half+1)*(TT/2); ++t) {
                float xr, xz, xn;
                proj20(&act4[(t*GB + blp)*RW4], wpr, wpz, wpn, bir, biz, bin, xr, xz, xn);
                float* px = xp + ((size_t)(dp*TT + t)*BB + bg)*30;
                *(v2f*)(px + 2*jp) = (v2f){xr, xz};
                px[20+jp] = xn;
            }
        }
        __syncthreads();
    }
    // layer 9: writes actG
    if (tid < 64) {
        scan_dual<true>(xpF, xpB,
                        whh + (size_t)(8*2    )*300, bhh + (size_t)(8*2    )*30,
                        whh + (size_t)(8*2 + 1)*300, bhh + (size_t)(8*2 + 1)*30,
                        (float*)act4, actG, bl, j, act_ln, b);
    }

    // ---- grid barrier (16 blocks, all co-resident) ----
    __threadfence();
    __syncthreads();
    if (tid == 0) {
        __hip_atomic_fetch_add(bar, 1u, __ATOMIC_ACQ_REL, __HIP_MEMORY_SCOPE_AGENT);
        while (__hip_atomic_load(bar, __ATOMIC_ACQUIRE, __HIP_MEMORY_SCOPE_AGENT) < (unsigned)NG)
            __builtin_amdgcn_s_sleep(1);
    }
    __syncthreads();
    __threadfence();

    // ---- head: rows r = grp*6 .. grp*6+5 (feat aliases act4) ----
    float* feat = (float*)act4;
    for (int u = tid; u < GB*336; u += 256) {
        int q = u / 336, v = u % 336;
        int r = grp*GB + q;
        int qq = v / 12, f = v % 12;
        int pair = r*28 + qq;           // t*32 + bb
        int t = pair / 32, bb = pair % 32;
        int jj = (f < 6) ? f : f - 6;
        float acc = (f < 6) ? 0.f : -1e30f;
        #pragma unroll
        for (int i = 0; i < 3; ++i) {
            #pragma unroll
            for (int kk = 0; kk < 3; ++kk) {
                float vv = actG[(size_t)(t*BB + bb*3 + i)*20 + jj*3 + kk];
                if (f < 6) acc += vv; else acc = fmaxf(acc, vv);
            }
        }
        feat[u] = (f < 6) ? acc*(1.f/9.f) : acc;
    }
    __syncthreads();
    if (tid < GB*19) {
        int q = tid / 19, o = tid % 19;
        int r = grp*GB + q;
        float acc = lin_b[o];
        const float* wrow = lin_w + o*336;
        const float* frow = feat + q*336;
        for (int v = 0; v < 336; ++v) acc = fmaf(frow[v], wrow[v], acc);
        out[r*19 + o] = frcp(1.f + __expf(-acc));
    }
}

extern "C" void kernel_launch(void* const* d_in, const int* in_sizes, int n_in,
                              void* d_out, int out_size, void* d_ws, size_t ws_size,
                              hipStream_t stream)
{
    const int*   x     = (const int*)  d_in[0];
    const float* emb   = (const float*)d_in[1];
    const float* wih0  = (const float*)d_in[2];
    const float* whh0  = (const float*)d_in[3];
    const float* bih0  = (const float*)d_in[4];
    const float* bhh0  = (const float*)d_in[5];
    const float* wih   = (const float*)d_in[6];
    const float* whh   = (const float*)d_in[7];
    const float* bih   = (const float*)d_in[8];
    const float* bhh   = (const float*)d_in[9];
    const float* lin_w = (const float*)d_in[10];
    const float* lin_b = (const float*)d_in[11];
    float* out = (float*)d_out;

    float* xp0  = (float*)d_ws;                    // 2*84*96*30 = 483840 floats
    float* actG = xp0 + (size_t)2*NTOK*30;         // 84*96*20   = 161280 floats
    unsigned int* bar = (unsigned int*)(actG + (size_t)NTOK*20);

    proj0_kernel<<<252, 256, 0, stream>>>(x, emb, wih0, bih0, xp0, bar);
    mega_kernel<<<NG, 256, 0, stream>>>(xp0, whh0, bhh0, wih, bih, whh, bhh,
                                        lin_w, lin_b, actG, bar, out);
}

// Round 9
// 456.374 us; speedup vs baseline: 1.1079x; 1.1079x over previous
//
#include <hip/hip_runtime.h>
#include <math.h>

#define TT 84
#define BB 96
#define GB 6            // batches per group
#define NG 16           // groups (NG*GB == BB)
#define NTOK (TT*BB)
#define RW4 6           // float4s per act row: 24 floats = [fwd 10 | pad 2 | bwd 10 | pad 2]

// Gate-argument pre-scaling folded into weights/biases:
//  r,z rows scaled by -log2(e)   -> sigm(a) = rcp(1 + exp2(arg))
//  n rows scaled by -2*log2(e)   -> tanh(x) = 2*rcp(1 + exp2(arg)) - 1
#define S_RZ (-1.4426950408889634f)
#define S_N  (-2.8853900817779268f)

typedef float v2f __attribute__((ext_vector_type(2)));
typedef float v4f __attribute__((ext_vector_type(4)));

__device__ __forceinline__ float frcp(float x)  { return __builtin_amdgcn_rcpf(x); }
__device__ __forceinline__ float fexp2(float x) { return __builtin_amdgcn_exp2f(x); }
__device__ __forceinline__ v2f   fma2(v2f a, v2f b, v2f c) {
    return __builtin_elementwise_fma(a, b, c);   // -> v_pk_fma_f32
}

// ---------------- layer-0 projection: emb gather + E=400 dot (pre-scaled) ----
// xp row layout (30 floats): [r0 z0 r1 z1 ... r9 z9 | n0..n9]
// One wave per 4 tokens: lanes 0..59 = (dir,gg) outputs; x-row float4 loads are
// wave-uniform (broadcast, 1 transaction); weights stream per-lane (L2-hot).
// 504 blocks x 4 waves -> ~8 waves/CU of TLP (vs 1/SIMD before).
__global__ __launch_bounds__(256) void proj0_kernel(
    const int* __restrict__ x, const float* __restrict__ emb,
    const float* __restrict__ wih0, const float* __restrict__ bih0,
    float* __restrict__ xp, unsigned int* __restrict__ bar)
{
    if (blockIdx.x == 0 && threadIdx.x == 0) bar[0] = 0u;  // re-zero grid barrier
    const int wv = threadIdx.x >> 6;           // wave 0..3
    const int g  = threadIdx.x & 63;
    if (g >= 60) return;
    const int tok0 = (blockIdx.x*4 + wv)*4;    // 4 tokens per wave
    const int dir = g / 30, gg = g % 30;
    const float sc = (gg < 20) ? S_RZ : S_N;
    const float bias = bih0[dir*30 + gg];
    // interleaved output index
    const int ch  = (gg < 20) ? (gg % 10) : (gg - 20);
    const int idx = (gg < 20) ? (ch*2 + gg/10) : (20 + ch);

    int rows[4];
    #pragma unroll
    for (int c = 0; c < 4; ++c) rows[c] = x[tok0 + c];

    const float4* w4 = ((const float4*)wih0) + (dir*30 + gg)*100;
    const float4* e4 = (const float4*)emb;
    float acc[4];
    #pragma unroll
    for (int c = 0; c < 4; ++c) acc[c] = bias;

    #pragma unroll 2
    for (int i4 = 0; i4 < 100; ++i4) {
        float4 w = w4[i4];
        #pragma unroll
        for (int c = 0; c < 4; ++c) {
            float4 xv = e4[(size_t)rows[c]*100 + i4];
            acc[c] += w.x*xv.x + w.y*xv.y + w.z*xv.z + w.w*xv.w;
        }
    }
    #pragma unroll
    for (int c = 0; c < 4; ++c) {
        int tok = tok0 + c;
        int t = tok / BB, b = tok % BB;
        xp[((size_t)((dir*TT + t)*BB + b))*30 + idx] = acc[c]*sc;
    }
}

// proj over 20 channels from a padded 24-float act row
__device__ __forceinline__ void proj20(
    const float4* A, const float* wpr, const float* wpz, const float* wpn,
    float bir, float biz, float bin, float& xr, float& xz, float& xn)
{
    float a[24];
    #pragma unroll
    for (int q = 0; q < 6; ++q) {
        a[4*q]=A[q].x; a[4*q+1]=A[q].y; a[4*q+2]=A[q].z; a[4*q+3]=A[q].w;
    }
    xr = bir; xz = biz; xn = bin;
    #pragma unroll
    for (int c = 0; c < 20; ++c) {
        float av = a[c + (c >= 10 ? 2 : 0)];
        xr = fmaf(wpr[c], av, xr); xz = fmaf(wpz[c], av, xz); xn = fmaf(wpn[c], av, xn);
    }
}

// ---------------- lean scan: pk-fp32 dots, LDS h-exchange, unroll-2 ----------
template<bool LAST>
__device__ __forceinline__ void scan_layer(
    const float* __restrict__ xb,       // xp + dir plane, layout [t][BB][30] interleaved
    const float* __restrict__ wh, const float* __restrict__ bh3,
    float* __restrict__ actF, float* __restrict__ actG,
    int bl, int j, bool act_ln, int b, int dir, int dt, int t0)
{
    // weight pairs: wr2[q] pairs with h pair {h2q, h2q+1}
    v2f wr2[5], wz2[5], wn2[5];
    {
        const v2f* p0 = (const v2f*)(wh + j*10);
        const v2f* p1 = (const v2f*)(wh + (10+j)*10);
        const v2f* p2 = (const v2f*)(wh + (20+j)*10);
        #pragma unroll
        for (int q = 0; q < 5; ++q) {
            wr2[q] = p0[q] * S_RZ;
            wz2[q] = p1[q] * S_RZ;
            wn2[q] = p2[q] * S_N;
        }
    }
    const v2f br2 = {bh3[j]*S_RZ,    0.f};
    const v2f bz2 = {bh3[10+j]*S_RZ, 0.f};
    const v2f bn2 = {bh3[20+j]*S_N,  0.f};

    v2f H0 = {0,0}, H1 = {0,0}, H2 = {0,0}, H3 = {0,0}, H4 = {0,0};
    float hown = 0.f;
    int t = t0;

    // 2-deep x prefetch, double-buffered (no shift moves)
    const int xoff = 2*j, noff = 20 + j;
    v2f  rzA = *(const v2f*)(xb + (size_t)(t0*BB + b)*30 + xoff);
    float xnA = xb[(size_t)(t0*BB + b)*30 + noff];
    v2f  rzB = *(const v2f*)(xb + (size_t)((t0+dt)*BB + b)*30 + xoff);
    float xnB = xb[(size_t)((t0+dt)*BB + b)*30 + noff];

    const float* arow = actF;   // act base (float view)

    #define GRU_STEP(RZ, XN)                                                  \
    {                                                                         \
        v2f ar = fma2(wr2[0], H0, br2);                                       \
        v2f az = fma2(wz2[0], H0, bz2);                                       \
        v2f an2 = fma2(wn2[0], H0, bn2);                                      \
        ar = fma2(wr2[1], H1, ar); az = fma2(wz2[1], H1, az); an2 = fma2(wn2[1], H1, an2); \
        ar = fma2(wr2[2], H2, ar); az = fma2(wz2[2], H2, az); an2 = fma2(wn2[2], H2, an2); \
        ar = fma2(wr2[3], H3, ar); az = fma2(wz2[3], H3, az); an2 = fma2(wn2[3], H3, an2); \
        ar = fma2(wr2[4], H4, ar); az = fma2(wz2[4], H4, az); an2 = fma2(wn2[4], H4, an2); \
        float r  = frcp(1.f + fexp2((RZ.x + ar.x) + ar.y));                   \
        float z  = frcp(1.f + fexp2((RZ.y + az.x) + az.y));                   \
        float an = fmaf(r, an2.x + an2.y, XN);                                \
        float n  = fmaf(2.f, frcp(1.f + fexp2(an)), -1.f);                    \
        float hnew = n + z*(hown - n);                                        \
        hown = hnew;                                                          \
        int rowf = (t*GB + bl)*24 + dir*12;                                   \
        ((float*)arow)[rowf + j] = hnew;                /* ds_write */        \
        const v4f* hr = (const v4f*)(arow + rowf);                            \
        v4f ha = hr[0], hb = hr[1];                      /* 2x ds_read_b128 */\
        v2f hc = *(const v2f*)(arow + rowf + 8);         /* ds_read_b64 */    \
        H0 = ha.xy; H1 = ha.zw; H2 = hb.xy; H3 = hb.zw; H4 = hc;              \
        __builtin_amdgcn_sched_barrier(0);                                    \
        if (LAST) { if (act_ln) actG[(size_t)(t*BB + b)*20 + dir*10 + j] = hnew; } \
    }

    #pragma unroll 1
    for (int s = 0; s < TT; s += 2) {
        // half A
        GRU_STEP(rzA, xnA)
        {
            int tp = t + 2*dt; tp = tp < 0 ? 0 : (tp > TT-1 ? TT-1 : tp);
            const float* px = xb + (size_t)(tp*BB + b)*30;
            rzA = *(const v2f*)(px + xoff); xnA = px[noff];
            t += dt;
        }
        // half B
        GRU_STEP(rzB, xnB)
        {
            int tp = t + 2*dt; tp = tp < 0 ? 0 : (tp > TT-1 ? TT-1 : tp);
            const float* px = xb + (size_t)(tp*BB + b)*30;
            rzB = *(const v2f*)(px + xoff); xnB = px[noff];
            t += dt;
        }
    }
    #undef GRU_STEP
}

// ---------------- mega: all 10 layers + head, 16 blocks x 256 ----------------
__global__ __launch_bounds__(256, 1) void mega_kernel(
    float* __restrict__ xp,             // read-write: layer-l inputs, overwritten per layer
    const float* __restrict__ whh0, const float* __restrict__ bhh0,
    const float* __restrict__ wih,  const float* __restrict__ bih,
    const float* __restrict__ whh,  const float* __restrict__ bhh,
    const float* __restrict__ lin_w, const float* __restrict__ lin_b,
    float* __restrict__ actG, unsigned int* __restrict__ bar,
    float* __restrict__ out)
{
    __shared__ float4 act4[TT*GB*RW4];    // 48384 B, single buffer

    const int tid  = threadIdx.x;
    const int grp  = blockIdx.x;

    // scan mapping (waves 0,1)
    const int dir  = (tid >> 6) & 1;
    const int lane = tid & 63;
    int bl = lane / 10; if (bl > 5) bl = 5;
    int j  = lane - bl*10; if (j > 9) j = 9;
    const bool act_ln = (lane < 60);
    const int b  = grp*GB + bl;
    const int dt = dir ? -1 : 1;
    const int t0 = dir ? TT-1 : 0;

    // boundary-proj mapping (240 of 256 threads: 2 t-halves x 2 dir x 6 b x 10 ch)
    const int half = tid / 120;
    const int prr  = tid % 120;
    const int dp   = prr / 60;
    const int prr2 = prr % 60;
    const int blp  = prr2 / 10;
    const int jp   = prr2 % 10;

    #pragma unroll 1
    for (int l = 0; l < 9; ++l) {
        if (tid < 128) {
            const float* wh  = (l == 0) ? (whh0 + dir*300)
                                        : (whh + (size_t)((l-1)*2 + dir)*300);
            const float* bh3 = (l == 0) ? (bhh0 + dir*30)
                                        : (bhh + (size_t)((l-1)*2 + dir)*30);
            scan_layer<false>(xp + (size_t)dir*TT*BB*30, wh, bh3,
                              (float*)act4, actG, bl, j, act_ln, b, dir, dt, t0);
        }
        __syncthreads();
        // boundary pass: xp for layer l+1 from act4, all 4 waves
        if (tid < 240) {
            const float* wi = wih + (size_t)(l*2 + dp)*600;
            const float* bi = bih + (size_t)(l*2 + dp)*30;
            float wpr[20], wpz[20], wpn[20];
            {
                const float4* p0 = (const float4*)(wi + jp*20);
                const float4* p1 = (const float4*)(wi + (10+jp)*20);
                const float4* p2 = (const float4*)(wi + (20+jp)*20);
                #pragma unroll
                for (int q = 0; q < 5; ++q) {
                    float4 a = p0[q]; wpr[4*q]=a.x*S_RZ; wpr[4*q+1]=a.y*S_RZ; wpr[4*q+2]=a.z*S_RZ; wpr[4*q+3]=a.w*S_RZ;
                    float4 c = p1[q]; wpz[4*q]=c.x*S_RZ; wpz[4*q+1]=c.y*S_RZ; wpz[4*q+2]=c.z*S_RZ; wpz[4*q+3]=c.w*S_RZ;
                    float4 d = p2[q]; wpn[4*q]=d.x*S_N;  wpn[4*q+1]=d.y*S_N;  wpn[4*q+2]=d.z*S_N;  wpn[4*q+3]=d.w*S_N;
                }
            }
            const float bir = bi[jp]*S_RZ, biz = bi[10+jp]*S_RZ, bin = bi[20+jp]*S_N;
            const int bg = grp*GB + blp;
            #pragma unroll 1
            for (int t = half*(TT/2); t < (half+1)*(TT/2); ++t) {
                float xr, xz, xn;
                proj20(&act4[(t*GB + blp)*RW4], wpr, wpz, wpn, bir, biz, bin, xr, xz, xn);
                float* px = xp + ((size_t)(dp*TT + t)*BB + bg)*30;
                *(v2f*)(px + 2*jp) = (v2f){xr, xz};
                px[20+jp] = xn;
            }
        }
        __syncthreads();
    }
    // layer 9: writes actG
    if (tid < 128) {
        const float* wh  = whh + (size_t)(8*2 + dir)*300;
        const float* bh3 = bhh + (size_t)(8*2 + dir)*30;
        scan_layer<true>(xp + (size_t)dir*TT*BB*30, wh, bh3,
                         (float*)act4, actG, bl, j, act_ln, b, dir, dt, t0);
    }

    // ---- grid barrier (16 blocks, all co-resident) ----
    __threadfence();
    __syncthreads();
    if (tid == 0) {
        __hip_atomic_fetch_add(bar, 1u, __ATOMIC_ACQ_REL, __HIP_MEMORY_SCOPE_AGENT);
        while (__hip_atomic_load(bar, __ATOMIC_ACQUIRE, __HIP_MEMORY_SCOPE_AGENT) < (unsigned)NG)
            __builtin_amdgcn_s_sleep(1);
    }
    __syncthreads();
    __threadfence();

    // ---- head: rows r = grp*6 .. grp*6+5 (feat aliases act4) ----
    float* feat = (float*)act4;
    for (int u = tid; u < GB*336; u += 256) {
        int q = u / 336, v = u % 336;
        int r = grp*GB + q;
        int qq = v / 12, f = v % 12;
        int pair = r*28 + qq;           // t*32 + bb
        int t = pair / 32, bb = pair % 32;
        int jj = (f < 6) ? f : f - 6;
        float acc = (f < 6) ? 0.f : -1e30f;
        #pragma unroll
        for (int i = 0; i < 3; ++i) {
            #pragma unroll
            for (int kk = 0; kk < 3; ++kk) {
                float vv = actG[(size_t)(t*BB + bb*3 + i)*20 + jj*3 + kk];
                if (f < 6) acc += vv; else acc = fmaxf(acc, vv);
            }
        }
        feat[u] = (f < 6) ? acc*(1.f/9.f) : acc;
    }
    __syncthreads();
    if (tid < GB*19) {
        int q = tid / 19, o = tid % 19;
        int r = grp*GB + q;
        float acc = lin_b[o];
        const float* wrow = lin_w + o*336;
        const float* frow = feat + q*336;
        for (int v = 0; v < 336; ++v) acc = fmaf(frow[v], wrow[v], acc);
        out[r*19 + o] = frcp(1.f + __expf(-acc));
    }
}

extern "C" void kernel_launch(void* const* d_in, const int* in_sizes, int n_in,
                              void* d_out, int out_size, void* d_ws, size_t ws_size,
                              hipStream_t stream)
{
    const int*   x     = (const int*)  d_in[0];
    const float* emb   = (const float*)d_in[1];
    const float* wih0  = (const float*)d_in[2];
    const float* whh0  = (const float*)d_in[3];
    const float* bih0  = (const float*)d_in[4];
    const float* bhh0  = (const float*)d_in[5];
    const float* wih   = (const float*)d_in[6];
    const float* whh   = (const float*)d_in[7];
    const float* bih   = (const float*)d_in[8];
    const float* bhh   = (const float*)d_in[9];
    const float* lin_w = (const float*)d_in[10];
    const float* lin_b = (const float*)d_in[11];
    float* out = (float*)d_out;

    float* xp0  = (float*)d_ws;                    // 2*84*96*30 = 483840 floats
    float* actG = xp0 + (size_t)2*NTOK*30;         // 84*96*20   = 161280 floats
    unsigned int* bar = (unsigned int*)(actG + (size_t)NTOK*20);

    proj0_kernel<<<504, 256, 0, stream>>>(x, emb, wih0, bih0, xp0, bar);
    mega_kernel<<<NG, 256, 0, stream>>>(xp0, whh0, bhh0, wih, bih, whh, bhh,
                                        lin_w, lin_b, actG, bar, out);
}